// Round 7
// baseline (139.723 us; speedup 1.0000x reference)
//
#include <hip/hip_runtime.h>

#define MT_EPS    1e-8f
#define GRID_N    8
#define NCELLS    64          // GRID_N^2
#define DOM       3.2f
#define INV_CELL  1.25f       // GRID_N / (2*DOM)
#define PAD       1e-3f       // conservative AABB pad >> fp slack of u/v tests
#define PT_BATCH  1024        // points per work item (4/thread * 256)
#define TRI_CHUNK 128         // tris per work item (staged to LDS, 6 KB)
#define ITEM_CAP  8192

__device__ __forceinline__ int cell_clamp(float x) {
    int c = (int)floorf((x + DOM) * INV_CELL);
    return c < 0 ? 0 : (c > GRID_N - 1 ? GRID_N - 1 : c);
}

// ---- K1: per-tri coef+AABB+histogram (blocks 0..nTriB) and per-point
//      cell histogram (remaining blocks). LDS-aggregated -> few global atomics.
__global__ __launch_bounds__(256) void mt_bin(
    const float* __restrict__ v1, const float* __restrict__ v2,
    const float* __restrict__ v3, const float* __restrict__ pts,
    float4* __restrict__ coef, int* __restrict__ rangePk,
    int* __restrict__ entCnt, int* __restrict__ ptCnt, int F, int npts)
{
    __shared__ int h[NCELLS];
    if (threadIdx.x < NCELLS) h[threadIdx.x] = 0;
    __syncthreads();
    int nTriB = (F + 255) >> 8;
    if ((int)blockIdx.x < nTriB) {
        int f = blockIdx.x * 256 + threadIdx.x;
        if (f < F) {
            float v1x=v1[3*f], v1y=v1[3*f+1], v1z=v1[3*f+2];
            float v2x=v2[3*f], v2y=v2[3*f+1], v2z=v2[3*f+2];
            float v3x=v3[3*f], v3y=v3[3*f+1], v3z=v3[3*f+2];
            float e1x=v2x-v1x, e1y=v2y-v1y, e1z=v2z-v1z;
            float e2x=v3x-v1x, e2y=v3y-v1y, e2z=v3z-v1z;
            float hx=-e2y, hy=e2x;                         // cross((0,0,1), e2)
            float a = e1x*hx + e1y*hy;                     // determinant
            float fi = (fabsf(a) > MT_EPS) ? (1.0f/a) : 0.0f;  // invalid -> all-zero -> tm=-EPS -> miss
            float cux=fi*hx, cuy=fi*hy;
            float cu0 = -(v1x*cux + v1y*cuy);
            float cvx=fi*e1y, cvy=-fi*e1x;
            float cv0 = -(v1x*cvx + v1y*cvy);
            float nx=e1y*e2z-e1z*e2y, ny=e1z*e2x-e1x*e2z, nz=e1x*e2y-e1y*e2x;
            float ctx=fi*nx, cty=fi*ny, ctz=fi*nz;
            float ct0 = -(v1x*ctx + v1y*cty + v1z*ctz) - MT_EPS;
            coef[3*f+0] = make_float4(cux, cuy, cu0, cvx);
            coef[3*f+1] = make_float4(cvy, cv0, ctx, cty);
            coef[3*f+2] = make_float4(ctz, ct0, 0.0f, 0.0f);
            // xy-AABB -> covered cell range (clamped; PAD is conservative)
            float xmn = fminf(v1x, fminf(v2x, v3x)) - PAD;
            float xmx = fmaxf(v1x, fmaxf(v2x, v3x)) + PAD;
            float ymn = fminf(v1y, fminf(v2y, v3y)) - PAD;
            float ymx = fmaxf(v1y, fmaxf(v2y, v3y)) + PAD;
            int cx0 = cell_clamp(xmn), cx1 = cell_clamp(xmx);
            int cy0 = cell_clamp(ymn), cy1 = cell_clamp(ymx);
            rangePk[f] = cx0 | (cx1 << 8) | (cy0 << 16) | (cy1 << 24);
            for (int cy = cy0; cy <= cy1; ++cy)
                for (int cx = cx0; cx <= cx1; ++cx)
                    atomicAdd(&h[cy * GRID_N + cx], 1);
        }
        __syncthreads();
        if (threadIdx.x < NCELLS && h[threadIdx.x])
            atomicAdd(&entCnt[threadIdx.x], h[threadIdx.x]);
    } else {
        int p = ((int)blockIdx.x - nTriB) * 256 + threadIdx.x;
        if (p < npts) {
            int cx = cell_clamp(pts[3*p]);
            int cy = cell_clamp(pts[3*p+1]);
            atomicAdd(&h[cy * GRID_N + cx], 1);
        }
        __syncthreads();
        if (threadIdx.x < NCELLS && h[threadIdx.x])
            atomicAdd(&ptCnt[threadIdx.x], h[threadIdx.x]);
    }
}

// ---- K2: single block. Exclusive scans (entry list; 4-aligned point list),
//      init cursors, emit work items (cell x ptBatch x triChunk).
__global__ __launch_bounds__(64) void mt_build(
    const int* __restrict__ entCnt, const int* __restrict__ ptCnt,
    int* __restrict__ entCur, int* __restrict__ ptCur,
    int4* __restrict__ items, int* __restrict__ nItemsOut)
{
    __shared__ int ts[NCELLS], ps[NCELLS], ib[NCELLS];
    int c = threadIdx.x;   // 64 threads == NCELLS
    if (c == 0) {
        int a = 0, b = 0, it = 0;
        for (int i = 0; i < NCELLS; ++i) {
            ts[i] = a; a += entCnt[i];
            ps[i] = b; b += (ptCnt[i] + 3) & ~3;          // 4-align for int4 loads
            int nb = ((ptCnt[i] + PT_BATCH - 1) / PT_BATCH)
                   * ((entCnt[i] + TRI_CHUNK - 1) / TRI_CHUNK);
            ib[i] = it; it += nb;
        }
        nItemsOut[0] = it < ITEM_CAP ? it : ITEM_CAP;
    }
    __syncthreads();
    entCur[c] = ts[c];
    ptCur[c]  = ps[c];
    int tc = entCnt[c], pc = ptCnt[c];
    int idx = ib[c];
    for (int i = 0; i < pc; i += PT_BATCH)
        for (int j = 0; j < tc; j += TRI_CHUNK) {
            if (idx < ITEM_CAP) {
                int pcnt = pc - i; if (pcnt > PT_BATCH)  pcnt = PT_BATCH;
                int tcnt = tc - j; if (tcnt > TRI_CHUNK) tcnt = TRI_CHUNK;
                items[idx] = make_int4(ps[c] + i, pcnt, ts[c] + j, tcnt);
            }
            ++idx;
        }
}

// ---- K3: scatter. Tri blocks: replicate 48B coef record into each covered
//      cell's contiguous segment (main-kernel staging loads are then coalesced,
//      no index gather). Point blocks: LDS-rank sort-by-cell (1 global atomic
//      per (block,cell) instead of per point).
__global__ __launch_bounds__(256) void mt_scatter(
    const float* __restrict__ pts, const float4* __restrict__ coef,
    const int* __restrict__ rangePk, int* __restrict__ entCur,
    int* __restrict__ ptCur, float4* __restrict__ cellCoef,
    int* __restrict__ sortedIdx, int F, int npts)
{
    __shared__ int h[NCELLS], gb[NCELLS];
    int nTriB = (F + 255) >> 8;
    if ((int)blockIdx.x < nTriB) {
        int f = blockIdx.x * 256 + threadIdx.x;
        if (f >= F) return;
        int r = rangePk[f];
        int cx0 = r & 255, cx1 = (r >> 8) & 255, cy0 = (r >> 16) & 255, cy1 = (r >> 24) & 255;
        float4 c0 = coef[3*f], c1 = coef[3*f+1], c2 = coef[3*f+2];
        for (int cy = cy0; cy <= cy1; ++cy)
            for (int cx = cx0; cx <= cx1; ++cx) {
                int pos = atomicAdd(&entCur[cy * GRID_N + cx], 1);
                cellCoef[3*pos+0] = c0;
                cellCoef[3*pos+1] = c1;
                cellCoef[3*pos+2] = c2;
            }
    } else {
        if (threadIdx.x < NCELLS) h[threadIdx.x] = 0;
        __syncthreads();
        int p = ((int)blockIdx.x - nTriB) * 256 + threadIdx.x;
        int cell = 0, rank = 0;
        bool ok = (p < npts);
        if (ok) {
            cell = cell_clamp(pts[3*p+1]) * GRID_N + cell_clamp(pts[3*p]);
            rank = atomicAdd(&h[cell], 1);          // LDS atomic: local rank
        }
        __syncthreads();
        if (threadIdx.x < NCELLS && h[threadIdx.x] > 0)
            gb[threadIdx.x] = atomicAdd(&ptCur[threadIdx.x], h[threadIdx.x]);
        __syncthreads();
        if (ok) sortedIdx[gb[cell] + rank] = p;
    }
}

// ---- K4: main. Grid-stride over items; per item: stage <=128 tri records
//      (contiguous, coalesced) to LDS; 4 cell-sorted points/thread; proven
//      13-VALU/test inner loop; fp32 atomicAdd epilogue (~200k atomics total).
__global__ __launch_bounds__(256) void mt_main(
    const int4* __restrict__ items, const int* __restrict__ nItemsPtr,
    const int* __restrict__ sortedIdx, const float* __restrict__ pts,
    const float4* __restrict__ cellCoef, float* __restrict__ out)
{
    __shared__ float4 sc[TRI_CHUNK * 3];   // 6 KB
    int nIt = *nItemsPtr;
    for (int b = blockIdx.x; b < nIt; b += gridDim.x) {
        int4 it = items[b];                // x=ptOff y=ptCnt z=entOff w=triCnt
        int nf4 = it.w * 3;
        for (int i = threadIdx.x; i < nf4; i += 256)
            sc[i] = cellCoef[(size_t)it.z * 3 + i];
        __syncthreads();

        int4 iv = ((const int4*)(sortedIdx + it.x))[threadIdx.x];  // it.x 4-aligned
        float px[4], py[4], pz[4];
        int id[4], cnt[4]; bool ok[4];
        #pragma unroll
        for (int k = 0; k < 4; ++k) {
            int lp = threadIdx.x * 4 + k;
            ok[k] = (lp < it.y);
            int g = ok[k] ? ((k==0)?iv.x:(k==1)?iv.y:(k==2)?iv.z:iv.w) : 0;
            id[k] = g;
            px[k] = pts[3*g]; py[k] = pts[3*g+1]; pz[k] = pts[3*g+2];
            cnt[k] = 0;
        }

        #pragma unroll 2
        for (int j = 0; j < it.w; ++j) {
            float4 c0 = sc[3*j+0];                       // uniform ds_read_b128
            float4 c1 = sc[3*j+1];
            float2 c2 = *(const float2*)&sc[3*j+2];      // uniform ds_read_b64
            #pragma unroll
            for (int k = 0; k < 4; ++k) {
                float u = fmaf(c0.x, px[k], fmaf(c0.y, py[k], c0.z));
                float v = fmaf(c0.w, px[k], fmaf(c1.x, py[k], c1.y));
                float t = fmaf(c1.z, px[k], fmaf(c1.w, py[k], fmaf(c2.x, pz[k], c2.y)));
                float w = 1.0f - (u + v);
                float m = fminf(fminf(fminf(u, v), t), w);   // v_min3 + v_min
                cnt[k] += __float_as_int(m) >> 31;           // -1 per miss
            }
        }
        #pragma unroll
        for (int k = 0; k < 4; ++k)
            if (ok[k]) atomicAdd(&out[id[k]], (float)(it.w + cnt[k]));  // exact int-valued fp
        __syncthreads();   // before restage (grid-stride case)
    }
}

extern "C" void kernel_launch(void* const* d_in, const int* in_sizes, int n_in,
                              void* d_out, int out_size, void* d_ws, size_t ws_size,
                              hipStream_t stream) {
    const float* pts = (const float*)d_in[0];   // [B,N,3]
    const float* v1  = (const float*)d_in[1];   // [F,3]
    const float* v2  = (const float*)d_in[2];
    const float* v3  = (const float*)d_in[3];
    float* out = (float*)d_out;                  // [B*N] counts
    int npts = in_sizes[0] / 3;                  // 65536
    int F    = in_sizes[1] / 3;                  // 2048

    // ---- workspace layout (16B-aligned chunks) ----
    char* w = (char*)d_ws;
    size_t off = 0;
    auto take = [&](size_t bytes) { void* p = w + off; off = (off + bytes + 15) & ~(size_t)15; return p; };
    float4* coef      = (float4*)take((size_t)F * 3 * sizeof(float4));    // 96 KB
    int*    rangePk   = (int*)   take((size_t)F * sizeof(int));
    int*    entCnt    = (int*)   take(NCELLS * sizeof(int));              // | contiguous
    int*    ptCnt     = (int*)   take(NCELLS * sizeof(int));              // | for one memset
    int*    entCur    = (int*)   take(NCELLS * sizeof(int));
    int*    ptCur     = (int*)   take(NCELLS * sizeof(int));
    int*    nItems    = (int*)   take(sizeof(int));
    int4*   items     = (int4*)  take((size_t)ITEM_CAP * sizeof(int4));   // 128 KB
    int*    sortedIdx = (int*)   take(((size_t)npts + 4 * NCELLS) * sizeof(int));
    float4* cellCoef  = (float4*)take((size_t)F * NCELLS * 3 * sizeof(float4)); // 6 MB abs-max
    (void)ws_size; // fits: ~6.8 MB, ws >= 8.4 MB (observed R6: tsplit=64 allocated)

    // zero histograms + output (atomics accumulate into both)
    hipMemsetAsync(entCnt, 0, 2 * NCELLS * sizeof(int), stream);
    hipMemsetAsync(d_out, 0, (size_t)out_size * sizeof(float), stream);

    int nTriB = (F + 255) >> 8;
    int nPtB  = (npts + 255) >> 8;
    mt_bin    <<<dim3(nTriB + nPtB), dim3(256), 0, stream>>>(v1, v2, v3, pts,
                 coef, rangePk, entCnt, ptCnt, F, npts);
    mt_build  <<<dim3(1), dim3(64), 0, stream>>>(entCnt, ptCnt, entCur, ptCur,
                 items, nItems);
    mt_scatter<<<dim3(nTriB + nPtB), dim3(256), 0, stream>>>(pts, coef, rangePk,
                 entCur, ptCur, cellCoef, sortedIdx, F, npts);
    mt_main   <<<dim3(1024), dim3(256), 0, stream>>>(items, nItems, sortedIdx,
                 pts, cellCoef, out);
}

// Round 8
// 105.365 us; speedup vs baseline: 1.3261x; 1.3261x over previous
//
#include <hip/hip_runtime.h>

#define MT_EPS     1e-8f
#define GRID_N     8
#define NCELLS     64          // GRID_N^2
#define DOM        3.2f
#define INV_CELL   1.25f       // GRID_N / (2*DOM)
#define PAD        1e-3f       // conservative AABB pad >> fp slack of u/v tests
#define PT_BATCH   2048        // points per work item (8/thread * 256)
#define TRI_CHUNK  64          // tris per work item (staged to LDS, 3 KB)
#define ITEM_CAP   8192
#define TRI_BLOCKS 2
#define PT_BLOCKS  64
#define K1T        1024        // threads for bin/scatter kernels

__device__ __forceinline__ int cell_clamp(float x) {
    int c = (int)floorf((x + DOM) * INV_CELL);
    return c < 0 ? 0 : (c > GRID_N - 1 ? GRID_N - 1 : c);
}

// ---- K1: tri blocks compute coefs + packed AABB cell range + per-block cell
//      histogram; point blocks compute pcell[] + per-block cell histogram.
//      NO global atomics: per-(block,cell) counts stored with plain stores.
__global__ __launch_bounds__(K1T) void mt_bin(
    const float* __restrict__ v1, const float* __restrict__ v2,
    const float* __restrict__ v3, const float* __restrict__ pts,
    float4* __restrict__ coef, int* __restrict__ rangePk,
    int* __restrict__ pcell, int* __restrict__ triBH, int* __restrict__ ptBH,
    int F, int npts)
{
    __shared__ int h[NCELLS];
    if (threadIdx.x < NCELLS) h[threadIdx.x] = 0;
    __syncthreads();
    if ((int)blockIdx.x < TRI_BLOCKS) {
        for (int f = blockIdx.x * K1T + threadIdx.x; f < F; f += TRI_BLOCKS * K1T) {
            float v1x=v1[3*f], v1y=v1[3*f+1], v1z=v1[3*f+2];
            float v2x=v2[3*f], v2y=v2[3*f+1], v2z=v2[3*f+2];
            float v3x=v3[3*f], v3y=v3[3*f+1], v3z=v3[3*f+2];
            float e1x=v2x-v1x, e1y=v2y-v1y, e1z=v2z-v1z;
            float e2x=v3x-v1x, e2y=v3y-v1y, e2z=v3z-v1z;
            float hx=-e2y, hy=e2x;                         // cross((0,0,1), e2)
            float a = e1x*hx + e1y*hy;                     // determinant
            float fi = (fabsf(a) > MT_EPS) ? (1.0f/a) : 0.0f; // invalid -> zero coefs -> miss
            float cux=fi*hx, cuy=fi*hy;
            float cu0 = -(v1x*cux + v1y*cuy);
            float cvx=fi*e1y, cvy=-fi*e1x;
            float cv0 = -(v1x*cvx + v1y*cvy);
            float nx=e1y*e2z-e1z*e2y, ny=e1z*e2x-e1x*e2z, nz=e1x*e2y-e1y*e2x;
            float ctx=fi*nx, cty=fi*ny, ctz=fi*nz;
            float ct0 = -(v1x*ctx + v1y*cty + v1z*ctz) - MT_EPS;
            coef[3*f+0] = make_float4(cux, cuy, cu0, cvx);
            coef[3*f+1] = make_float4(cvy, cv0, ctx, cty);
            coef[3*f+2] = make_float4(ctz, ct0, 0.0f, 0.0f);
            float xmn = fminf(v1x, fminf(v2x, v3x)) - PAD;
            float xmx = fmaxf(v1x, fmaxf(v2x, v3x)) + PAD;
            float ymn = fminf(v1y, fminf(v2y, v3y)) - PAD;
            float ymx = fmaxf(v1y, fmaxf(v2y, v3y)) + PAD;
            int cx0 = cell_clamp(xmn), cx1 = cell_clamp(xmx);
            int cy0 = cell_clamp(ymn), cy1 = cell_clamp(ymx);
            rangePk[f] = cx0 | (cx1 << 8) | (cy0 << 16) | (cy1 << 24);
            for (int cy = cy0; cy <= cy1; ++cy)
                for (int cx = cx0; cx <= cx1; ++cx)
                    atomicAdd(&h[cy * GRID_N + cx], 1);    // LDS atomic (fast)
        }
        __syncthreads();
        if (threadIdx.x < NCELLS)
            triBH[blockIdx.x * NCELLS + threadIdx.x] = h[threadIdx.x];  // plain store
    } else {
        int b = (int)blockIdx.x - TRI_BLOCKS;
        for (int p = b * K1T + threadIdx.x; p < npts; p += PT_BLOCKS * K1T) {
            int c = cell_clamp(pts[3*p+1]) * GRID_N + cell_clamp(pts[3*p]);
            pcell[p] = c;
            atomicAdd(&h[c], 1);                           // LDS atomic
        }
        __syncthreads();
        if (threadIdx.x < NCELLS)
            ptBH[b * NCELLS + threadIdx.x] = h[threadIdx.x];
    }
}

// ---- K2: ONE block. LDS-staged scans: per-(block,cell) bases, cell segment
//      offsets (pt segments 8-aligned), work-item emission. All deterministic.
__global__ __launch_bounds__(256) void mt_build(
    const int* __restrict__ triBH, const int* __restrict__ ptBH,
    int* __restrict__ triBase, int* __restrict__ ptBase,
    int4* __restrict__ items, int* __restrict__ nItemsOut)
{
    __shared__ int sT[TRI_BLOCKS * NCELLS];     // hist -> in-place bases
    __shared__ int sP[PT_BLOCKS * NCELLS];      // 16 KB
    __shared__ int entC[NCELLS], ptC[NCELLS];
    __shared__ int entOff[NCELLS], ptOff[NCELLS], itOff[NCELLS];
    int tid = threadIdx.x;
    for (int i = tid; i < TRI_BLOCKS * NCELLS; i += 256) sT[i] = triBH[i];
    for (int i = tid; i < PT_BLOCKS * NCELLS;  i += 256) sP[i] = ptBH[i];
    __syncthreads();
    if (tid < NCELLS) {                         // per-cell scan over blocks
        int run = 0;
        for (int b = 0; b < TRI_BLOCKS; ++b) {
            int v = sT[b * NCELLS + tid]; sT[b * NCELLS + tid] = run; run += v;
        }
        entC[tid] = run;
        int rp = 0;
        for (int b = 0; b < PT_BLOCKS; ++b) {
            int v = sP[b * NCELLS + tid]; sP[b * NCELLS + tid] = rp; rp += v;
        }
        ptC[tid] = rp;
    }
    __syncthreads();
    if (tid == 0) {                             // cell-level exclusive scans
        int to = 0, po = 0, io = 0;
        for (int c = 0; c < NCELLS; ++c) {
            entOff[c] = to; to += entC[c];
            ptOff[c]  = po; po += (ptC[c] + 7) & ~7;       // 8-align segments
            int ni = ((ptC[c] + PT_BATCH - 1) / PT_BATCH)
                   * ((entC[c] + TRI_CHUNK - 1) / TRI_CHUNK);
            itOff[c] = io; io += ni;
        }
        nItemsOut[0] = io < ITEM_CAP ? io : ITEM_CAP;
    }
    __syncthreads();
    for (int i = tid; i < TRI_BLOCKS * NCELLS; i += 256)
        triBase[i] = sT[i] + entOff[i % NCELLS];           // fold segment offset
    for (int i = tid; i < PT_BLOCKS * NCELLS;  i += 256)
        ptBase[i]  = sP[i] + ptOff[i % NCELLS];
    if (tid < NCELLS) {                         // emit this cell's work items
        int c = tid, idx = itOff[c], pc = ptC[c], tc = entC[c];
        for (int i = 0; i < pc; i += PT_BATCH)
            for (int j = 0; j < tc; j += TRI_CHUNK) {
                if (idx < ITEM_CAP) {
                    int pcnt = pc - i; if (pcnt > PT_BATCH)  pcnt = PT_BATCH;
                    int tcnt = tc - j; if (tcnt > TRI_CHUNK) tcnt = TRI_CHUNK;
                    items[idx] = make_int4(ptOff[c] + i, pcnt, entOff[c] + j, tcnt);
                }
                ++idx;
            }
    }
}

// ---- K3: scatter with block-local LDS ranks + precomputed bases.
//      Plain stores only; 4B tri indices (coefs gathered later from L2).
__global__ __launch_bounds__(K1T) void mt_scatter(
    const int* __restrict__ rangePk, const int* __restrict__ pcell,
    const int* __restrict__ triBase, const int* __restrict__ ptBase,
    int* __restrict__ cellTriIdx, int* __restrict__ sortedIdx, int F, int npts)
{
    __shared__ int h[NCELLS];
    if (threadIdx.x < NCELLS) h[threadIdx.x] = 0;
    __syncthreads();
    if ((int)blockIdx.x < TRI_BLOCKS) {
        for (int f = blockIdx.x * K1T + threadIdx.x; f < F; f += TRI_BLOCKS * K1T) {
            int r = rangePk[f];
            int cx0 = r & 255, cx1 = (r >> 8) & 255;
            int cy0 = (r >> 16) & 255, cy1 = (r >> 24) & 255;
            for (int cy = cy0; cy <= cy1; ++cy)
                for (int cx = cx0; cx <= cx1; ++cx) {
                    int c = cy * GRID_N + cx;
                    int rank = atomicAdd(&h[c], 1);        // LDS atomic
                    cellTriIdx[triBase[blockIdx.x * NCELLS + c] + rank] = f;
                }
        }
    } else {
        int b = (int)blockIdx.x - TRI_BLOCKS;
        for (int p = b * K1T + threadIdx.x; p < npts; p += PT_BLOCKS * K1T) {
            int c = pcell[p];
            int rank = atomicAdd(&h[c], 1);                // LDS atomic
            sortedIdx[ptBase[b * NCELLS + c] + rank] = p;
        }
    }
}

// ---- K4: main. Grid-stride items; stage <=64 tri coef records via index
//      gather (L2-resident); 8 cell-sorted points/thread; 13-VALU/test loop;
//      ~350K mostly-unique-address fp32 atomics in epilogue.
__global__ __launch_bounds__(256) void mt_main(
    const int4* __restrict__ items, const int* __restrict__ nItemsPtr,
    const int* __restrict__ sortedIdx, const float* __restrict__ pts,
    const float4* __restrict__ coef, const int* __restrict__ cellTriIdx,
    float* __restrict__ out)
{
    __shared__ float4 sc[TRI_CHUNK * 3];       // 3 KB
    int nIt = *nItemsPtr;
    for (int b = blockIdx.x; b < nIt; b += gridDim.x) {
        int4 it = items[b];                    // x=ptOff y=ptCnt z=triOff w=triCnt
        int n3 = it.w * 3;
        for (int i = threadIdx.x; i < n3; i += 256) {
            int tri = cellTriIdx[it.z + i / 3];
            sc[i] = coef[tri * 3 + i % 3];
        }
        __syncthreads();

        int base = it.x + threadIdx.x * 8;     // it.x 8-aligned
        int4 iv0 = *(const int4*)(sortedIdx + base);
        int4 iv1 = *(const int4*)(sortedIdx + base + 4);
        int gid[8]; bool ok[8];
        float px[8], py[8], pz[8];
        int cnt[8];
        #pragma unroll
        for (int k = 0; k < 8; ++k) {
            int lp = threadIdx.x * 8 + k;
            ok[k] = (lp < it.y);
            int g = (k < 4) ? ((k==0)?iv0.x:(k==1)?iv0.y:(k==2)?iv0.z:iv0.w)
                            : ((k==4)?iv1.x:(k==5)?iv1.y:(k==6)?iv1.z:iv1.w);
            g = ok[k] ? g : 0;                 // pad slots hold garbage -> guard
            gid[k] = g;
            px[k] = pts[3*g]; py[k] = pts[3*g+1]; pz[k] = pts[3*g+2];
            cnt[k] = 0;
        }

        #pragma unroll 2
        for (int j = 0; j < it.w; ++j) {
            float4 c0 = sc[3*j+0];                       // uniform ds_read_b128
            float4 c1 = sc[3*j+1];
            float2 c2 = *(const float2*)&sc[3*j+2];      // uniform ds_read_b64
            #pragma unroll
            for (int k = 0; k < 8; ++k) {
                float u = fmaf(c0.x, px[k], fmaf(c0.y, py[k], c0.z));
                float v = fmaf(c0.w, px[k], fmaf(c1.x, py[k], c1.y));
                float t = fmaf(c1.z, px[k], fmaf(c1.w, py[k], fmaf(c2.x, pz[k], c2.y)));
                float w = 1.0f - (u + v);
                float m = fminf(fminf(fminf(u, v), t), w);   // v_min3 + v_min
                cnt[k] += __float_as_int(m) >> 31;           // -1 per miss
            }
        }
        #pragma unroll
        for (int k = 0; k < 8; ++k)
            if (ok[k]) atomicAdd(&out[gid[k]], (float)(it.w + cnt[k]));
        __syncthreads();                        // before restage (grid-stride)
    }
}

extern "C" void kernel_launch(void* const* d_in, const int* in_sizes, int n_in,
                              void* d_out, int out_size, void* d_ws, size_t ws_size,
                              hipStream_t stream) {
    const float* pts = (const float*)d_in[0];   // [B,N,3]
    const float* v1  = (const float*)d_in[1];   // [F,3]
    const float* v2  = (const float*)d_in[2];
    const float* v3  = (const float*)d_in[3];
    float* out = (float*)d_out;                  // [B*N] counts
    int npts = in_sizes[0] / 3;                  // 65536
    int F    = in_sizes[1] / 3;                  // 2048

    // ---- workspace layout (16B-aligned chunks), total ~1.6 MB ----
    char* w = (char*)d_ws;
    size_t off = 0;
    auto take = [&](size_t bytes) { void* p = w + off; off = (off + bytes + 15) & ~(size_t)15; return p; };
    float4* coef       = (float4*)take((size_t)F * 3 * sizeof(float4));          // 96 KB
    int*    rangePk    = (int*)   take((size_t)F * sizeof(int));
    int*    pcell      = (int*)   take((size_t)npts * sizeof(int));              // 256 KB
    int*    triBH      = (int*)   take(TRI_BLOCKS * NCELLS * sizeof(int));
    int*    ptBH       = (int*)   take(PT_BLOCKS * NCELLS * sizeof(int));        // 16 KB
    int*    triBase    = (int*)   take(TRI_BLOCKS * NCELLS * sizeof(int));
    int*    ptBase     = (int*)   take(PT_BLOCKS * NCELLS * sizeof(int));
    int*    nItems     = (int*)   take(sizeof(int));
    int4*   items      = (int4*)  take((size_t)ITEM_CAP * sizeof(int4));         // 128 KB
    int*    sortedIdx  = (int*)   take(((size_t)npts + 8 * NCELLS) * sizeof(int));
    int*    cellTriIdx = (int*)   take((size_t)F * NCELLS * sizeof(int));        // 512 KB worst
    (void)ws_size;  // ~1.6 MB total; ws >= 8 MB observed in prior rounds

    hipMemsetAsync(d_out, 0, (size_t)out_size * sizeof(float), stream);

    mt_bin    <<<dim3(TRI_BLOCKS + PT_BLOCKS), dim3(K1T), 0, stream>>>(
                 v1, v2, v3, pts, coef, rangePk, pcell, triBH, ptBH, F, npts);
    mt_build  <<<dim3(1), dim3(256), 0, stream>>>(
                 triBH, ptBH, triBase, ptBase, items, nItems);
    mt_scatter<<<dim3(TRI_BLOCKS + PT_BLOCKS), dim3(K1T), 0, stream>>>(
                 rangePk, pcell, triBase, ptBase, cellTriIdx, sortedIdx, F, npts);
    mt_main   <<<dim3(1024), dim3(256), 0, stream>>>(
                 items, nItems, sortedIdx, pts, coef, cellTriIdx, out);
}

// Round 10
// 72.592 us; speedup vs baseline: 1.9248x; 1.4515x over previous
//
#include <hip/hip_runtime.h>

#define MT_EPS     1e-8f
#define GRID_N     8
#define NCELLS     64          // GRID_N^2
#define DOM        3.2f
#define INV_CELL   1.25f       // GRID_N / (2*DOM)
#define PAD        1e-3f       // conservative AABB pad >> fp slack of u/v tests
#define PT_BATCH   2048        // points per work item (8/thread * 256)
#define TRI_CHUNK  64          // tris per work item (staged to LDS, 3 KB)
#define K_ROWS     32          // max chunks/cell = ceil(F/TRI_CHUNK) worst case
#define ITEM_CAP   8192
#define TRI_BLOCKS 2
#define PT_BLOCKS  16          // 16 blocks * 1024 thr * 4 pts = 65536
#define K1T        1024

__device__ __forceinline__ int cell_clamp(float x) {
    int c = (int)floorf((x + DOM) * INV_CELL);
    return c < 0 ? 0 : (c > GRID_N - 1 ? GRID_N - 1 : c);
}

// ---- K1: tri blocks -> coefs + AABB cell range + per-block cell histogram;
//      point blocks -> pcell[] + per-block cell histogram. Plain stores only.
__global__ __launch_bounds__(K1T) void mt_bin(
    const float* __restrict__ v1, const float* __restrict__ v2,
    const float* __restrict__ v3, const float* __restrict__ pts,
    float4* __restrict__ coef, int* __restrict__ rangePk,
    int* __restrict__ pcell, int* __restrict__ triBH, int* __restrict__ ptBH,
    int F, int npts)
{
    __shared__ int h[NCELLS];
    if (threadIdx.x < NCELLS) h[threadIdx.x] = 0;
    __syncthreads();
    if ((int)blockIdx.x < TRI_BLOCKS) {
        for (int f = blockIdx.x * K1T + threadIdx.x; f < F; f += TRI_BLOCKS * K1T) {
            float v1x=v1[3*f], v1y=v1[3*f+1], v1z=v1[3*f+2];
            float v2x=v2[3*f], v2y=v2[3*f+1], v2z=v2[3*f+2];
            float v3x=v3[3*f], v3y=v3[3*f+1], v3z=v3[3*f+2];
            float e1x=v2x-v1x, e1y=v2y-v1y, e1z=v2z-v1z;
            float e2x=v3x-v1x, e2y=v3y-v1y, e2z=v3z-v1z;
            float hx=-e2y, hy=e2x;                          // cross((0,0,1), e2)
            float a = e1x*hx + e1y*hy;                      // determinant
            float fi = (fabsf(a) > MT_EPS) ? (1.0f/a) : 0.0f; // invalid -> zero coefs -> miss
            float cux=fi*hx, cuy=fi*hy;
            float cu0 = -(v1x*cux + v1y*cuy);
            float cvx=fi*e1y, cvy=-fi*e1x;
            float cv0 = -(v1x*cvx + v1y*cvy);
            float nx=e1y*e2z-e1z*e2y, ny=e1z*e2x-e1x*e2z, nz=e1x*e2y-e1y*e2x;
            float ctx=fi*nx, cty=fi*ny, ctz=fi*nz;
            float ct0 = -(v1x*ctx + v1y*cty + v1z*ctz) - MT_EPS;
            coef[3*f+0] = make_float4(cux, cuy, cu0, cvx);
            coef[3*f+1] = make_float4(cvy, cv0, ctx, cty);
            coef[3*f+2] = make_float4(ctz, ct0, 0.0f, 0.0f);
            float xmn = fminf(v1x, fminf(v2x, v3x)) - PAD;
            float xmx = fmaxf(v1x, fmaxf(v2x, v3x)) + PAD;
            float ymn = fminf(v1y, fminf(v2y, v3y)) - PAD;
            float ymx = fmaxf(v1y, fmaxf(v2y, v3y)) + PAD;
            int cx0 = cell_clamp(xmn), cx1 = cell_clamp(xmx);
            int cy0 = cell_clamp(ymn), cy1 = cell_clamp(ymx);
            rangePk[f] = cx0 | (cx1 << 8) | (cy0 << 16) | (cy1 << 24);
            for (int cy = cy0; cy <= cy1; ++cy)
                for (int cx = cx0; cx <= cx1; ++cx)
                    atomicAdd(&h[cy * GRID_N + cx], 1);     // LDS atomic
        }
        __syncthreads();
        if (threadIdx.x < NCELLS)
            triBH[blockIdx.x * NCELLS + threadIdx.x] = h[threadIdx.x];
    } else {
        int b = (int)blockIdx.x - TRI_BLOCKS;
        for (int p0 = (b * K1T + threadIdx.x) * 4; p0 < npts; p0 += PT_BLOCKS * K1T * 4) {
            if (p0 + 3 < npts) {
                const float4* pv = (const float4*)(pts + (size_t)p0 * 3);
                float4 A = pv[0], B = pv[1], C = pv[2];
                int c0 = cell_clamp(A.y)*GRID_N + cell_clamp(A.x);
                int c1 = cell_clamp(B.x)*GRID_N + cell_clamp(A.w);
                int c2 = cell_clamp(B.w)*GRID_N + cell_clamp(B.z);
                int c3 = cell_clamp(C.z)*GRID_N + cell_clamp(C.y);
                *(int4*)(pcell + p0) = make_int4(c0, c1, c2, c3);
                atomicAdd(&h[c0], 1); atomicAdd(&h[c1], 1);
                atomicAdd(&h[c2], 1); atomicAdd(&h[c3], 1);
            } else {
                for (int p = p0; p < npts; ++p) {
                    int c = cell_clamp(pts[3*p+1])*GRID_N + cell_clamp(pts[3*p]);
                    pcell[p] = c;
                    atomicAdd(&h[c], 1);
                }
            }
        }
        __syncthreads();
        if (threadIdx.x < NCELLS)
            ptBH[b * NCELLS + threadIdx.x] = h[threadIdx.x];
    }
}

// ---- K2: ONE block. Scans -> per-(block,cell) bases, cell offsets (pt
//      segments 8-aligned), work items, cellMeta, origIdx pad slots = -1.
//      cellMeta: [0..63] ptStart, [64] total, [65..128] nchunk.
//      Item: x=spOff y=ptCnt z=triOff w=triCnt|(chunkIdx<<16)
__global__ __launch_bounds__(256) void mt_build(
    const int* __restrict__ triBH, const int* __restrict__ ptBH,
    int* __restrict__ triBase, int* __restrict__ ptBase,
    int* __restrict__ cellMeta, int* __restrict__ origIdx,
    int4* __restrict__ items, int* __restrict__ nItemsOut)
{
    __shared__ int sT[TRI_BLOCKS * NCELLS];
    __shared__ int sP[PT_BLOCKS * NCELLS];
    __shared__ int entC[NCELLS], ptC[NCELLS];
    __shared__ int entOff[NCELLS], ptOff[NCELLS], itOff[NCELLS];
    int tid = threadIdx.x;
    for (int i = tid; i < TRI_BLOCKS * NCELLS; i += 256) sT[i] = triBH[i];
    for (int i = tid; i < PT_BLOCKS * NCELLS;  i += 256) sP[i] = ptBH[i];
    __syncthreads();
    if (tid < NCELLS) {
        int run = 0;
        for (int b = 0; b < TRI_BLOCKS; ++b) {
            int v = sT[b * NCELLS + tid]; sT[b * NCELLS + tid] = run; run += v;
        }
        entC[tid] = run;
        int rp = 0;
        for (int b = 0; b < PT_BLOCKS; ++b) {
            int v = sP[b * NCELLS + tid]; sP[b * NCELLS + tid] = rp; rp += v;
        }
        ptC[tid] = rp;
    }
    __syncthreads();
    if (tid == 0) {
        int to = 0, po = 0, io = 0;
        for (int c = 0; c < NCELLS; ++c) {
            entOff[c] = to; to += entC[c];
            ptOff[c]  = po; po += (ptC[c] + 7) & ~7;        // 8-aligned segments
            int ni = ((ptC[c] + PT_BATCH - 1) / PT_BATCH)
                   * ((entC[c] + TRI_CHUNK - 1) / TRI_CHUNK);
            itOff[c] = io; io += ni;
        }
        nItemsOut[0] = io < ITEM_CAP ? io : ITEM_CAP;
        cellMeta[NCELLS] = po;                              // total sorted slots
    }
    __syncthreads();
    for (int i = tid; i < TRI_BLOCKS * NCELLS; i += 256)
        triBase[i] = sT[i] + entOff[i % NCELLS];
    for (int i = tid; i < PT_BLOCKS * NCELLS;  i += 256)
        ptBase[i]  = sP[i] + ptOff[i % NCELLS];
    if (tid < NCELLS) {
        int c = tid;
        int nk = (entC[c] + TRI_CHUNK - 1) / TRI_CHUNK;
        cellMeta[c] = ptOff[c];
        cellMeta[NCELLS + 1 + c] = nk;
        int e = ptOff[c] + ptC[c], ae = ptOff[c] + ((ptC[c] + 7) & ~7);
        for (int q = e; q < ae; ++q) origIdx[q] = -1;       // pad slots skipped in mt_out
        int idx = itOff[c], pc = ptC[c], tc = entC[c];
        for (int i = 0; i < pc; i += PT_BATCH)
            for (int k = 0; k < nk; ++k) {
                if (idx < ITEM_CAP) {
                    int j = k * TRI_CHUNK;
                    int tcnt = tc - j; if (tcnt > TRI_CHUNK) tcnt = TRI_CHUNK;
                    int pcnt = pc - i; if (pcnt > PT_BATCH)  pcnt = PT_BATCH;
                    items[idx] = make_int4(ptOff[c] + i, pcnt, entOff[c] + j,
                                           tcnt | (k << 16));
                }
                ++idx;
            }
    }
}

// ---- K3: scatter via block-local LDS ranks + precomputed bases (no global
//      atomics). Tri side: 4B indices per covered cell. Point side: point
//      COORDS in cell-sorted order + origIdx for the final scatter-store.
__global__ __launch_bounds__(K1T) void mt_scatter(
    const float* __restrict__ pts, const int* __restrict__ rangePk,
    const int* __restrict__ pcell, const int* __restrict__ triBase,
    const int* __restrict__ ptBase, int* __restrict__ cellTriIdx,
    float* __restrict__ sortedPts, int* __restrict__ origIdx, int F, int npts)
{
    __shared__ int h[NCELLS];
    if (threadIdx.x < NCELLS) h[threadIdx.x] = 0;
    __syncthreads();
    if ((int)blockIdx.x < TRI_BLOCKS) {
        for (int f = blockIdx.x * K1T + threadIdx.x; f < F; f += TRI_BLOCKS * K1T) {
            int r = rangePk[f];
            int cx0 = r & 255, cx1 = (r >> 8) & 255;
            int cy0 = (r >> 16) & 255, cy1 = (r >> 24) & 255;
            for (int cy = cy0; cy <= cy1; ++cy)
                for (int cx = cx0; cx <= cx1; ++cx) {
                    int c = cy * GRID_N + cx;
                    int rank = atomicAdd(&h[c], 1);         // LDS atomic
                    cellTriIdx[triBase[blockIdx.x * NCELLS + c] + rank] = f;
                }
        }
    } else {
        int b = (int)blockIdx.x - TRI_BLOCKS;
        for (int p0 = (b * K1T + threadIdx.x) * 4; p0 < npts; p0 += PT_BLOCKS * K1T * 4) {
            if (p0 + 3 < npts) {
                const float4* pv = (const float4*)(pts + (size_t)p0 * 3);
                float4 A = pv[0], B = pv[1], C = pv[2];
                int4 cc = *(const int4*)(pcell + p0);
                float X[4] = {A.x, A.w, B.z, C.y};
                float Y[4] = {A.y, B.x, B.w, C.z};
                float Z[4] = {A.z, B.y, C.x, C.w};
                int cs[4] = {cc.x, cc.y, cc.z, cc.w};
                #pragma unroll
                for (int k = 0; k < 4; ++k) {
                    int rank = atomicAdd(&h[cs[k]], 1);
                    int pos = ptBase[b * NCELLS + cs[k]] + rank;
                    sortedPts[3*pos+0] = X[k];
                    sortedPts[3*pos+1] = Y[k];
                    sortedPts[3*pos+2] = Z[k];
                    origIdx[pos] = p0 + k;
                }
            } else {
                for (int p = p0; p < npts; ++p) {
                    int c = pcell[p];
                    int rank = atomicAdd(&h[c], 1);
                    int pos = ptBase[b * NCELLS + c] + rank;
                    sortedPts[3*pos+0] = pts[3*p+0];
                    sortedPts[3*pos+1] = pts[3*p+1];
                    sortedPts[3*pos+2] = pts[3*p+2];
                    origIdx[pos] = p;
                }
            }
        }
    }
}

// ---- K4: main. Per item: stage <=64 tri coefs to LDS; ACTIVE threads
//      (tid*8 < ptCnt -- R9 bug: this guard was missing, causing cross-cell
//      partial[] overwrites) load 8 sorted points coalesced, run the
//      13-VALU/test loop, store 8 ushort counts as one uint4. No atomics.
__global__ __launch_bounds__(256) void mt_main(
    const int4* __restrict__ items, const int* __restrict__ nItemsPtr,
    const float* __restrict__ sortedPts, const float4* __restrict__ coef,
    const int* __restrict__ cellTriIdx, unsigned short* __restrict__ partial,
    int nppad)
{
    __shared__ float4 sc[TRI_CHUNK * 3];       // 3 KB
    int nIt = *nItemsPtr;
    for (int b = blockIdx.x; b < nIt; b += gridDim.x) {
        int4 it = items[b];                    // x=spOff y=ptCnt z=triOff w=tcnt|(chunk<<16)
        int tcnt = it.w & 0xffff;
        int krow = it.w >> 16;
        int n3 = tcnt * 3;
        for (int i = threadIdx.x; i < n3; i += 256) {
            int tri = cellTriIdx[it.z + i / 3];
            sc[i] = coef[tri * 3 + i % 3];
        }
        __syncthreads();

        if ((int)threadIdx.x * 8 < it.y) {     // active: tiles padded segment exactly
            int sp0 = it.x + threadIdx.x * 8;  // it.x 8-aligned -> 16B-aligned loads
            const float4* pv = (const float4*)(sortedPts + (size_t)sp0 * 3);
            float4 A = pv[0], B = pv[1], C = pv[2], D = pv[3], E = pv[4], G = pv[5];
            float px[8] = {A.x, A.w, B.z, C.y, D.x, D.w, E.z, G.y};
            float py[8] = {A.y, B.x, B.w, C.z, D.y, E.x, E.w, G.z};
            float pz[8] = {A.z, B.y, C.x, C.w, D.z, E.y, G.x, G.w};
            int cnt[8];
            #pragma unroll
            for (int k = 0; k < 8; ++k) cnt[k] = 0;

            #pragma unroll 2
            for (int j = 0; j < tcnt; ++j) {
                float4 c0 = sc[3*j+0];                       // uniform ds_read_b128
                float4 c1 = sc[3*j+1];
                float2 c2 = *(const float2*)&sc[3*j+2];      // uniform ds_read_b64
                #pragma unroll
                for (int k = 0; k < 8; ++k) {
                    float u = fmaf(c0.x, px[k], fmaf(c0.y, py[k], c0.z));
                    float v = fmaf(c0.w, px[k], fmaf(c1.x, py[k], c1.y));
                    float t = fmaf(c1.z, px[k], fmaf(c1.w, py[k], fmaf(c2.x, pz[k], c2.y)));
                    float w = 1.0f - (u + v);
                    float m = fminf(fminf(fminf(u, v), t), w);   // v_min3 + v_min
                    cnt[k] += __float_as_int(m) >> 31;           // -1 per miss
                }
            }
            // hits this chunk = tcnt + cnt[k] in [0,64] -> ushort. Pad slots
            // (within this segment's 8-group) get garbage values but are
            // skipped via origIdx=-1 in mt_out.
            uint4 o;
            o.x = (unsigned)(unsigned short)(tcnt + cnt[0]) | ((unsigned)(unsigned short)(tcnt + cnt[1]) << 16);
            o.y = (unsigned)(unsigned short)(tcnt + cnt[2]) | ((unsigned)(unsigned short)(tcnt + cnt[3]) << 16);
            o.z = (unsigned)(unsigned short)(tcnt + cnt[4]) | ((unsigned)(unsigned short)(tcnt + cnt[5]) << 16);
            o.w = (unsigned)(unsigned short)(tcnt + cnt[6]) | ((unsigned)(unsigned short)(tcnt + cnt[7]) << 16);
            *(uint4*)(partial + (size_t)krow * nppad + sp0) = o;
        }
        __syncthreads();                        // before restage
    }
}

// ---- K5: out[origIdx[sp]] = sum over k < nchunk(cell(sp)) of partial[k][sp].
//      Coalesced row reads; every real point written exactly once -> no memset.
__global__ __launch_bounds__(256) void mt_out(
    const unsigned short* __restrict__ partial, const int* __restrict__ cellMeta,
    const int* __restrict__ origIdx, float* __restrict__ out, int nppad)
{
    __shared__ int start[NCELLS + 1], nchk[NCELLS];
    int tid = threadIdx.x;
    if (tid < NCELLS + 1) start[tid] = cellMeta[tid];
    if (tid < NCELLS)     nchk[tid]  = cellMeta[NCELLS + 1 + tid];
    __syncthreads();
    int sp0 = (blockIdx.x * 256 + tid) * 4;
    if (sp0 >= start[NCELLS]) return;
    int lo = 0, hi = NCELLS - 1;                 // find cell: start[c] <= sp0 < start[c+1]
    while (lo < hi) { int mid = (lo + hi) >> 1; if (start[mid+1] <= sp0) lo = mid + 1; else hi = mid; }
    int nk = nchk[lo];
    int s0 = 0, s1 = 0, s2 = 0, s3 = 0;
    for (int k = 0; k < nk; ++k) {
        uint2 v = *(const uint2*)(partial + (size_t)k * nppad + sp0);
        s0 += v.x & 0xffff; s1 += v.x >> 16;
        s2 += v.y & 0xffff; s3 += v.y >> 16;
    }
    int4 oi = *(const int4*)(origIdx + sp0);
    if (oi.x >= 0) out[oi.x] = (float)s0;
    if (oi.y >= 0) out[oi.y] = (float)s1;
    if (oi.z >= 0) out[oi.z] = (float)s2;
    if (oi.w >= 0) out[oi.w] = (float)s3;
}

extern "C" void kernel_launch(void* const* d_in, const int* in_sizes, int n_in,
                              void* d_out, int out_size, void* d_ws, size_t ws_size,
                              hipStream_t stream) {
    const float* pts = (const float*)d_in[0];   // [B,N,3]
    const float* v1  = (const float*)d_in[1];   // [F,3]
    const float* v2  = (const float*)d_in[2];
    const float* v3  = (const float*)d_in[3];
    float* out = (float*)d_out;                  // [B*N] counts
    int npts = in_sizes[0] / 3;                  // 65536
    int F    = in_sizes[1] / 3;                  // 2048

    int nppad = (npts + 8 * NCELLS + 7) & ~7;    // sorted-slot capacity (66048)

    // ---- workspace layout (16B-aligned chunks), total ~6.3 MB (ws >= 8.5 MB) ----
    char* w = (char*)d_ws;
    size_t off = 0;
    auto take = [&](size_t bytes) { void* p = w + off; off = (off + bytes + 15) & ~(size_t)15; return p; };
    float4* coef       = (float4*)take((size_t)F * 3 * sizeof(float4));
    int*    rangePk    = (int*)   take((size_t)F * sizeof(int));
    int*    pcell      = (int*)   take((size_t)npts * sizeof(int));
    int*    triBH      = (int*)   take(TRI_BLOCKS * NCELLS * sizeof(int));
    int*    ptBH       = (int*)   take(PT_BLOCKS * NCELLS * sizeof(int));
    int*    triBase    = (int*)   take(TRI_BLOCKS * NCELLS * sizeof(int));
    int*    ptBase     = (int*)   take(PT_BLOCKS * NCELLS * sizeof(int));
    int*    cellMeta   = (int*)   take((2 * NCELLS + 1) * sizeof(int));
    int*    nItems     = (int*)   take(sizeof(int));
    int4*   itemsBuf   = (int4*)  take((size_t)ITEM_CAP * sizeof(int4));
    int*    origIdx    = (int*)   take((size_t)nppad * sizeof(int));
    float*  sortedPts  = (float*) take((size_t)nppad * 3 * sizeof(float));
    int*    cellTriIdx = (int*)   take((size_t)F * NCELLS * sizeof(int));
    unsigned short* partial = (unsigned short*)take((size_t)K_ROWS * nppad * sizeof(unsigned short));
    (void)ws_size;

    mt_bin    <<<dim3(TRI_BLOCKS + PT_BLOCKS), dim3(K1T), 0, stream>>>(
                 v1, v2, v3, pts, coef, rangePk, pcell, triBH, ptBH, F, npts);
    mt_build  <<<dim3(1), dim3(256), 0, stream>>>(
                 triBH, ptBH, triBase, ptBase, cellMeta, origIdx, itemsBuf, nItems);
    mt_scatter<<<dim3(TRI_BLOCKS + PT_BLOCKS), dim3(K1T), 0, stream>>>(
                 pts, rangePk, pcell, triBase, ptBase, cellTriIdx,
                 sortedPts, origIdx, F, npts);
    mt_main   <<<dim3(1024), dim3(256), 0, stream>>>(
                 itemsBuf, nItems, sortedPts, coef, cellTriIdx, partial, nppad);
    int nq = (nppad + 3) / 4;
    mt_out    <<<dim3((nq + 255) / 256), dim3(256), 0, stream>>>(
                 partial, cellMeta, origIdx, out, nppad);
}